// Round 7
// baseline (104.989 us; speedup 1.0000x reference)
//
#include <hip/hip_runtime.h>
#include <utility>

// reference == inverse(M M^T + EPS*I) per pixel, M = x[b,:,:,h,w]^T (16x64)
// x: [B=4, C=64, K=16, H=128, W=128] f32 ; out: [B,H,W,16,16] f32
// Fully fused, 64 px/block, 256 threads:
//   phase 1: gram via global_load_lds dbuf staging, 4 waves x 34 pairs (acc[34])
//   phase 2: acc -> LDS tri[136][67] (+EPS diag)
//   phase 3: ALL 4 waves invert: wave w -> pixels [16w,16w+16), lanes 0-15
//            (4 independent latency chains, CU stays busy in aligned phase)
//   phase 4: all 256 threads gather-store coalesced to out
// LDS: union{stage 32KB, tri 36.4KB} = 36.4KB -> 4 blocks/CU.

#define EPSR 1e-6f

__device__ __host__ constexpr int rowof(int t) {
    int i = 0;
    while ((i + 1) * (i + 2) / 2 <= t) ++i;
    return i;
}
__device__ __host__ constexpr int colof(int t) { return t - rowof(t) * (rowof(t) + 1) / 2; }

__device__ __forceinline__ constexpr int tidx(int i, int j) {  // i >= j
    return i * (i + 1) / 2 + j;
}

#define GLOAD_LDS16(gp, lp)                                                       \
    __builtin_amdgcn_global_load_lds(                                             \
        (const __attribute__((address_space(1))) void*)(gp),                      \
        (__attribute__((address_space(3))) void*)(lp), 16, 0, 0)

// ---------------- pair-split template machinery ----------------

template<int P>
__device__ __forceinline__ void fma_pair(const float (&m)[16], float& a) {
    a = fmaf(m[rowof(P)], m[colof(P)], a);
}

template<int G, int... TT>
__device__ __forceinline__ void fma_group(const float (&m)[16], float (&acc)[34],
                                          std::integer_sequence<int, TT...>) {
    (fma_pair<G * 34 + TT>(m, acc[TT]), ...);
}

template<int G>
__device__ __forceinline__ void chunk_fma4(const float* __restrict__ buf, int lane,
                                           float (&acc)[34]) {
    #pragma unroll
    for (int cs = 0; cs < 4; ++cs) {
        float m[16];
        #pragma unroll
        for (int k = 0; k < 16; ++k) m[k] = buf[(cs * 16 + k) * 64 + lane];
        fma_group<G>(m, acc, std::make_integer_sequence<int, 34>{});
    }
}

template<int P>
__device__ __forceinline__ void store_tri_pair(float* __restrict__ tri, int lane, float v) {
    constexpr bool diag = (rowof(P) == colof(P));
    tri[P * 67 + lane] = diag ? (v + EPSR) : v;
}

template<int G, int... TT>
__device__ __forceinline__ void store_tri_group(float* __restrict__ tri, int lane,
                                                const float (&acc)[34],
                                                std::integer_sequence<int, TT...>) {
    (store_tri_pair<G * 34 + TT>(tri, lane, acc[TT]), ...);
}

// ---------------- fused kernel ----------------

union SMem {
    float stage[2][4096];      // 2 x 16 KB: [c'(=wv)*16+k][px 64]
    float tri[136 * 67];       // 36.4 KB; row = pair index, col = pixel
};

__global__ __launch_bounds__(256, 4)
void fused_gram_inv(const float* __restrict__ x, float* __restrict__ out) {
    __shared__ __align__(16) SMem sm;

    const int tid = threadIdx.x;
    const int lane = tid & 63;
    const int wv = tid >> 6;
    const int p0 = blockIdx.x * 64;
    const int b = blockIdx.x >> 8;
    const int hw0 = p0 & 16383;

    // staging src: lane l covers k-row (l>>4) of a 4-row span, px (l&15)*4..+3
    const float* gbase = x + (size_t)b * 16777216 + hw0
                           + (size_t)(lane >> 4) * 16384 + (size_t)(lane & 15) * 4;

    float acc[34];
    #pragma unroll
    for (int t = 0; t < 34; ++t) acc[t] = 0.0f;

    // wave wv stages channel c0+wv: 4 instrs x (4 k-rows x 64 px) = 4 KB
    auto STAGE = [&](int bufi, int c0) {
        #pragma unroll
        for (int q = 0; q < 4; ++q) {
            GLOAD_LDS16(gbase + (size_t)(c0 + wv) * 262144 + (size_t)(q * 4) * 16384,
                        &sm.stage[bufi][(wv * 16 + q * 4) * 64]);
        }
    };

    // ---- phase 1: gram ----
    STAGE(0, 0);
    for (int t = 0; t < 16; ++t) {
        __syncthreads();                              // vmcnt(0) drain + barrier
        if (t < 15) STAGE((t + 1) & 1, 4 * (t + 1));  // prefetch next chunk
        const float* buf = sm.stage[t & 1];
        switch (wv) {
            case 0:  chunk_fma4<0>(buf, lane, acc); break;
            case 1:  chunk_fma4<1>(buf, lane, acc); break;
            case 2:  chunk_fma4<2>(buf, lane, acc); break;
            default: chunk_fma4<3>(buf, lane, acc); break;
        }
    }
    __syncthreads();   // all stage reads done before aliasing stage as tri

    // ---- phase 2: acc -> tri (+EPS on diag) ----
    switch (wv) {
        case 0:  store_tri_group<0>(sm.tri, lane, acc, std::make_integer_sequence<int, 34>{}); break;
        case 1:  store_tri_group<1>(sm.tri, lane, acc, std::make_integer_sequence<int, 34>{}); break;
        case 2:  store_tri_group<2>(sm.tri, lane, acc, std::make_integer_sequence<int, 34>{}); break;
        default: store_tri_group<3>(sm.tri, lane, acc, std::make_integer_sequence<int, 34>{}); break;
    }
    __syncthreads();

    // ---- phase 3: 4 waves, wave w inverts px [16w,16w+16), lanes 0-15 ----
    if (lane < 16) {
        float* lp = &sm.tri[(wv << 4) + lane];
        #define SL(t) lp[(t) * 67]

        // Cholesky: diag holds 1/L[j][j]
        #pragma unroll
        for (int j = 0; j < 16; ++j) {
            float rj[16];
            #pragma unroll
            for (int q = 0; q < j; ++q) rj[q] = SL(tidx(j, q));
            float d = SL(tidx(j, j));
            #pragma unroll
            for (int q = 0; q < j; ++q) d = fmaf(-rj[q], rj[q], d);
            const float invd = 1.0f / sqrtf(d);
            SL(tidx(j, j)) = invd;
            #pragma unroll
            for (int i = j + 1; i < 16; ++i) {
                float v = SL(tidx(i, j));
                #pragma unroll
                for (int q = 0; q < j; ++q) v = fmaf(-SL(tidx(i, q)), rj[q], v);
                SL(tidx(i, j)) = v * invd;
            }
        }

        // M = L^{-1} in place (diag already inverted)
        #pragma unroll
        for (int j = 0; j < 16; ++j) {
            float col[16];
            col[j] = SL(tidx(j, j));
            #pragma unroll
            for (int i = j + 1; i < 16; ++i) {
                float sum = SL(tidx(i, j)) * col[j];
                #pragma unroll
                for (int q = j + 1; q < i; ++q)
                    sum = fmaf(SL(tidx(i, q)), col[q], sum);
                const float mii = SL(tidx(i, i));
                const float mij = -mii * sum;
                col[i] = mij;
                SL(tidx(i, j)) = mij;
            }
        }

        // A^{-1} = M^T M in place
        #pragma unroll
        for (int j = 0; j < 16; ++j) {
            float cj[16];
            #pragma unroll
            for (int q = j; q < 16; ++q) cj[q] = SL(tidx(q, j));
            #pragma unroll
            for (int i = j; i < 16; ++i) {
                float sum = 0.0f;
                if (i == j) {
                    #pragma unroll
                    for (int q = j; q < 16; ++q) sum = fmaf(cj[q], cj[q], sum);
                } else {
                    #pragma unroll
                    for (int q = i; q < 16; ++q) sum = fmaf(SL(tidx(q, i)), cj[q], sum);
                }
                SL(tidx(i, j)) = sum;
            }
        }
        #undef SL
    }
    __syncthreads();

    // ---- phase 4: gather-store, thread = output element e, loop over pixels ----
    const int e = tid;                  // 0..255 -> (i,j)
    const int i = e >> 4, j = e & 15;
    const int hi = i > j ? i : j;
    const int lo = i + j - hi;
    const int trow = hi * (hi + 1) / 2 + lo;
    float* gout = out + (size_t)p0 * 256;
    #pragma unroll 8
    for (int a = 0; a < 64; ++a) {
        gout[(size_t)a * 256 + e] = sm.tri[trow * 67 + a];
    }
}

extern "C" void kernel_launch(void* const* d_in, const int* in_sizes, int n_in,
                              void* d_out, int out_size, void* d_ws, size_t ws_size,
                              hipStream_t stream) {
    const float* x = (const float*)d_in[0];
    float* out = (float*)d_out;
    hipLaunchKernelGGL(fused_gram_inv, dim3(1024), dim3(256), 0, stream, x, out);
}

// Round 8
// 91.899 us; speedup vs baseline: 1.1424x; 1.1424x over previous
//
#include <hip/hip_runtime.h>
#include <utility>

// reference == inverse(M M^T + EPS*I) per pixel, M = x[b,:,:,h,w]^T (16x64)
// x: [B=4, C=64, K=16, H=128, W=128] f32 ; out: [B,H,W,16,16] f32
// Fully fused, 64 px/block, 256 threads:
//   phase 1: gram, 3-buffer global_load_lds pipeline with COUNTED vmcnt waits
//            (loads stay in flight across barriers; no vmcnt(0) drain per iter)
//   phase 2: acc -> LDS tri[136][67] (+EPS diag)
//   phase 3: wave 0 inverts all 64 pixels in LDS (64 lanes = 64 px; round-6 form,
//            issue-efficient: round-7's 4x16-lane split QUADRUPLED issue, -20us)
//   phase 4: all 256 threads gather-store coalesced to out
// LDS: union{stage 3x16KB, tri 36.4KB} = 48KB -> 3 blocks/CU.

#define EPSR 1e-6f

__device__ __host__ constexpr int rowof(int t) {
    int i = 0;
    while ((i + 1) * (i + 2) / 2 <= t) ++i;
    return i;
}
__device__ __host__ constexpr int colof(int t) { return t - rowof(t) * (rowof(t) + 1) / 2; }

__device__ __forceinline__ constexpr int tidx(int i, int j) {  // i >= j
    return i * (i + 1) / 2 + j;
}

#define GLOAD_LDS16(gp, lp)                                                       \
    __builtin_amdgcn_global_load_lds(                                             \
        (const __attribute__((address_space(1))) void*)(gp),                      \
        (__attribute__((address_space(3))) void*)(lp), 16, 0, 0)

// ---------------- pair-split template machinery ----------------

template<int P>
__device__ __forceinline__ void fma_pair(const float (&m)[16], float& a) {
    a = fmaf(m[rowof(P)], m[colof(P)], a);
}

template<int G, int... TT>
__device__ __forceinline__ void fma_group(const float (&m)[16], float (&acc)[34],
                                          std::integer_sequence<int, TT...>) {
    (fma_pair<G * 34 + TT>(m, acc[TT]), ...);
}

template<int G>
__device__ __forceinline__ void chunk_fma4(const float* __restrict__ buf, int lane,
                                           float (&acc)[34]) {
    #pragma unroll
    for (int cs = 0; cs < 4; ++cs) {
        float m[16];
        #pragma unroll
        for (int k = 0; k < 16; ++k) m[k] = buf[(cs * 16 + k) * 64 + lane];
        fma_group<G>(m, acc, std::make_integer_sequence<int, 34>{});
    }
}

template<int P>
__device__ __forceinline__ void store_tri_pair(float* __restrict__ tri, int lane, float v) {
    constexpr bool diag = (rowof(P) == colof(P));
    tri[P * 67 + lane] = diag ? (v + EPSR) : v;
}

template<int G, int... TT>
__device__ __forceinline__ void store_tri_group(float* __restrict__ tri, int lane,
                                                const float (&acc)[34],
                                                std::integer_sequence<int, TT...>) {
    (store_tri_pair<G * 34 + TT>(tri, lane, acc[TT]), ...);
}

// ---------------- fused kernel ----------------

union SMem {
    float stage[3][4096];      // 3 x 16 KB: [c'(=wv)*16+k][px 64]
    float tri[136 * 67];       // 36.4 KB; row = pair index, col = pixel
};

__global__ __launch_bounds__(256, 3)
void fused_gram_inv(const float* __restrict__ x, float* __restrict__ out) {
    __shared__ __align__(16) SMem sm;

    const int tid = threadIdx.x;
    const int lane = tid & 63;
    const int wv = tid >> 6;
    const int p0 = blockIdx.x * 64;
    const int b = blockIdx.x >> 8;
    const int hw0 = p0 & 16383;

    // staging src: lane l covers k-row (l>>4) of a 4-row span, px (l&15)*4..+3
    const float* gbase = x + (size_t)b * 16777216 + hw0
                           + (size_t)(lane >> 4) * 16384 + (size_t)(lane & 15) * 4;

    float acc[34];
    #pragma unroll
    for (int t = 0; t < 34; ++t) acc[t] = 0.0f;

    // wave wv stages channel c0+wv: 4 instrs x (4 k-rows x 64 px) = 4 KB
    auto STAGE = [&](int bufi, int c0) {
        #pragma unroll
        for (int q = 0; q < 4; ++q) {
            GLOAD_LDS16(gbase + (size_t)(c0 + wv) * 262144 + (size_t)(q * 4) * 16384,
                        &sm.stage[bufi][(wv * 16 + q * 4) * 64]);
        }
    };

    // ---- phase 1: gram, 3-buffer counted-vmcnt pipeline ----
    STAGE(0, 0);       // chunk 0
    STAGE(1, 4);       // chunk 1  (8 loads outstanding per wave)
    for (int t = 0; t < 15; ++t) {
        // oldest 4 loads (chunk t) landed; chunk t+1's 4 may stay in flight
        asm volatile("s_waitcnt vmcnt(4)" ::: "memory");
        __builtin_amdgcn_s_barrier();
        if (t < 14) STAGE((t + 2) % 3, 4 * (t + 2));   // chunk t+2, 2-iter flight
        const float* buf = sm.stage[t % 3];
        switch (wv) {
            case 0:  chunk_fma4<0>(buf, lane, acc); break;
            case 1:  chunk_fma4<1>(buf, lane, acc); break;
            case 2:  chunk_fma4<2>(buf, lane, acc); break;
            default: chunk_fma4<3>(buf, lane, acc); break;
        }
    }
    {   // peeled last iteration: full drain
        asm volatile("s_waitcnt vmcnt(0)" ::: "memory");
        __builtin_amdgcn_s_barrier();
        const float* buf = sm.stage[15 % 3];
        switch (wv) {
            case 0:  chunk_fma4<0>(buf, lane, acc); break;
            case 1:  chunk_fma4<1>(buf, lane, acc); break;
            case 2:  chunk_fma4<2>(buf, lane, acc); break;
            default: chunk_fma4<3>(buf, lane, acc); break;
        }
    }
    __syncthreads();   // all stage reads done before aliasing stage as tri

    // ---- phase 2: acc -> tri (+EPS on diag) ----
    switch (wv) {
        case 0:  store_tri_group<0>(sm.tri, lane, acc, std::make_integer_sequence<int, 34>{}); break;
        case 1:  store_tri_group<1>(sm.tri, lane, acc, std::make_integer_sequence<int, 34>{}); break;
        case 2:  store_tri_group<2>(sm.tri, lane, acc, std::make_integer_sequence<int, 34>{}); break;
        default: store_tri_group<3>(sm.tri, lane, acc, std::make_integer_sequence<int, 34>{}); break;
    }
    __syncthreads();

    // ---- phase 3: wave 0 inverts (lane = pixel), round-6 issue-efficient form ----
    if (wv == 0) {
        float* lp = &sm.tri[lane];
        #define SL(t) lp[(t) * 67]

        // Cholesky: diag holds 1/L[j][j]
        #pragma unroll
        for (int j = 0; j < 16; ++j) {
            float rj[16];
            #pragma unroll
            for (int q = 0; q < j; ++q) rj[q] = SL(tidx(j, q));
            float d = SL(tidx(j, j));
            #pragma unroll
            for (int q = 0; q < j; ++q) d = fmaf(-rj[q], rj[q], d);
            const float invd = 1.0f / sqrtf(d);
            SL(tidx(j, j)) = invd;
            #pragma unroll
            for (int i = j + 1; i < 16; ++i) {
                float v = SL(tidx(i, j));
                #pragma unroll
                for (int q = 0; q < j; ++q) v = fmaf(-SL(tidx(i, q)), rj[q], v);
                SL(tidx(i, j)) = v * invd;
            }
        }

        // M = L^{-1} in place (diag already inverted)
        #pragma unroll
        for (int j = 0; j < 16; ++j) {
            float col[16];
            col[j] = SL(tidx(j, j));
            #pragma unroll
            for (int i = j + 1; i < 16; ++i) {
                float sum = SL(tidx(i, j)) * col[j];
                #pragma unroll
                for (int q = j + 1; q < i; ++q)
                    sum = fmaf(SL(tidx(i, q)), col[q], sum);
                const float mii = SL(tidx(i, i));
                const float mij = -mii * sum;
                col[i] = mij;
                SL(tidx(i, j)) = mij;
            }
        }

        // A^{-1} = M^T M in place
        #pragma unroll
        for (int j = 0; j < 16; ++j) {
            float cj[16];
            #pragma unroll
            for (int q = j; q < 16; ++q) cj[q] = SL(tidx(q, j));
            #pragma unroll
            for (int i = j; i < 16; ++i) {
                float sum = 0.0f;
                if (i == j) {
                    #pragma unroll
                    for (int q = j; q < 16; ++q) sum = fmaf(cj[q], cj[q], sum);
                } else {
                    #pragma unroll
                    for (int q = i; q < 16; ++q) sum = fmaf(SL(tidx(q, i)), cj[q], sum);
                }
                SL(tidx(i, j)) = sum;
            }
        }
        #undef SL
    }
    __syncthreads();

    // ---- phase 4: gather-store, thread = output element e, loop over pixels ----
    const int e = tid;                  // 0..255 -> (i,j)
    const int i = e >> 4, j = e & 15;
    const int hi = i > j ? i : j;
    const int lo = i + j - hi;
    const int trow = hi * (hi + 1) / 2 + lo;
    float* gout = out + (size_t)p0 * 256;
    #pragma unroll 8
    for (int a = 0; a < 64; ++a) {
        gout[(size_t)a * 256 + e] = sm.tri[trow * 67 + a];
    }
}

extern "C" void kernel_launch(void* const* d_in, const int* in_sizes, int n_in,
                              void* d_out, int out_size, void* d_ws, size_t ws_size,
                              hipStream_t stream) {
    const float* x = (const float*)d_in[0];
    float* out = (float*)d_out;
    hipLaunchKernelGGL(fused_gram_inv, dim3(1024), dim3(256), 0, stream, x, out);
}

// Round 9
// 78.341 us; speedup vs baseline: 1.3402x; 1.1731x over previous
//
#include <hip/hip_runtime.h>
#include <utility>

// reference == inverse(M M^T + EPS*I) per pixel, M = x[b,:,:,h,w]^T (16x64)
// x: [B=4, C=64, K=16, H=128, W=128] f32 ; out: [B,H,W,16,16] f32
// Fused, 64 px/block, 128 threads (2 waves):
//   phase 1: gram via global_load_lds dbuf (round-6 __syncthreads form, 4 blocks/CU),
//            2-way pair split: wave w computes pairs [68w,68w+68) -> acc[68]
//            (halves the 4x redundant per-pixel LDS m-reads of round 6)
//   phase 2: acc -> LDS tri[136][67] (+EPS diag)
//   phase 3: wave 0, lane = pixel: load 136 from tri -> REGISTER Cholesky ->
//            L^-1 -> M^T M (pure-VALU chains, no LDS in dependency path) -> tri
//   phase 4: 128 threads gather-store coalesced (each thread 2 elements)
// LDS: union{stage 2x16KB, tri 36.4KB} = 36.4KB -> 4 blocks/CU, 2 waves/SIMD
// -> VGPR cap 256, room for phase-3's ~170.

#define EPSR 1e-6f

__device__ __host__ constexpr int rowof(int t) {
    int i = 0;
    while ((i + 1) * (i + 2) / 2 <= t) ++i;
    return i;
}
__device__ __host__ constexpr int colof(int t) { return t - rowof(t) * (rowof(t) + 1) / 2; }

__device__ __forceinline__ constexpr int tidx(int i, int j) {  // i >= j
    return i * (i + 1) / 2 + j;
}

#define GLOAD_LDS16(gp, lp)                                                       \
    __builtin_amdgcn_global_load_lds(                                             \
        (const __attribute__((address_space(1))) void*)(gp),                      \
        (__attribute__((address_space(3))) void*)(lp), 16, 0, 0)

// ---------------- pair-split template machinery (68/wave) ----------------

template<int P>
__device__ __forceinline__ void fma_pair(const float (&m)[16], float& a) {
    a = fmaf(m[rowof(P)], m[colof(P)], a);
}

template<int G, int... TT>
__device__ __forceinline__ void fma_group(const float (&m)[16], float (&acc)[68],
                                          std::integer_sequence<int, TT...>) {
    (fma_pair<G * 68 + TT>(m, acc[TT]), ...);
}

template<int G>
__device__ __forceinline__ void chunk_fma4(const float* __restrict__ buf, int lane,
                                           float (&acc)[68]) {
    #pragma unroll
    for (int cs = 0; cs < 4; ++cs) {
        float m[16];
        #pragma unroll
        for (int k = 0; k < 16; ++k) m[k] = buf[(cs * 16 + k) * 64 + lane];
        fma_group<G>(m, acc, std::make_integer_sequence<int, 68>{});
    }
}

template<int P>
__device__ __forceinline__ void store_tri_pair(float* __restrict__ tri, int lane, float v) {
    constexpr bool diag = (rowof(P) == colof(P));
    tri[P * 67 + lane] = diag ? (v + EPSR) : v;
}

template<int G, int... TT>
__device__ __forceinline__ void store_tri_group(float* __restrict__ tri, int lane,
                                                const float (&acc)[68],
                                                std::integer_sequence<int, TT...>) {
    (store_tri_pair<G * 68 + TT>(tri, lane, acc[TT]), ...);
}

// ---------------- fused kernel ----------------

union SMem {
    float stage[2][4096];      // 2 x 16 KB: [cs(0..3)*16+k][px 64]
    float tri[136 * 67];       // 36.4 KB; row = pair index, col = pixel
};

__global__ __launch_bounds__(128, 2)
void fused_gram_inv(const float* __restrict__ x, float* __restrict__ out) {
    __shared__ __align__(16) SMem sm;

    const int tid = threadIdx.x;
    const int lane = tid & 63;
    const int wv = tid >> 6;                  // 0 or 1
    const int p0 = blockIdx.x * 64;
    const int b = blockIdx.x >> 8;
    const int hw0 = p0 & 16383;

    // staging src: lane l covers k-row (l>>4) of a 4-row span, px (l&15)*4..+3
    const float* gbase = x + (size_t)b * 16777216 + hw0
                           + (size_t)(lane >> 4) * 16384 + (size_t)(lane & 15) * 4;

    float acc[68];
    #pragma unroll
    for (int t = 0; t < 68; ++t) acc[t] = 0.0f;

    // wave wv stages cs = wv and wv+2 of each 4-c chunk: 8 instrs x 1 KB
    auto STAGE = [&](int bufi, int c0) {
        #pragma unroll
        for (int s = 0; s < 2; ++s) {
            const int cs = wv + 2 * s;
            #pragma unroll
            for (int q = 0; q < 4; ++q) {
                GLOAD_LDS16(gbase + (size_t)(c0 + cs) * 262144 + (size_t)(q * 4) * 16384,
                            &sm.stage[bufi][(cs * 16 + q * 4) * 64]);
            }
        }
    };

    // ---- phase 1: gram, round-6 dbuf form ----
    STAGE(0, 0);
    for (int t = 0; t < 16; ++t) {
        __syncthreads();                              // vmcnt(0) drain + barrier
        if (t < 15) STAGE((t + 1) & 1, 4 * (t + 1));  // prefetch next chunk
        const float* buf = sm.stage[t & 1];
        if (wv == 0) chunk_fma4<0>(buf, lane, acc);
        else         chunk_fma4<1>(buf, lane, acc);
    }
    __syncthreads();   // all stage reads done before aliasing stage as tri

    // ---- phase 2: acc -> tri (+EPS on diag) ----
    if (wv == 0) store_tri_group<0>(sm.tri, lane, acc, std::make_integer_sequence<int, 68>{});
    else         store_tri_group<1>(sm.tri, lane, acc, std::make_integer_sequence<int, 68>{});
    __syncthreads();

    // ---- phase 3: wave 0, lane = pixel, REGISTER inversion ----
    if (wv == 0) {
        float s[136];
        #pragma unroll
        for (int t = 0; t < 136; ++t) s[t] = sm.tri[t * 67 + lane];

        // Cholesky in place: off-diag = L[i][j], diag = 1/L[j][j]
        #pragma unroll
        for (int j = 0; j < 16; ++j) {
            float d = s[tidx(j, j)];
            #pragma unroll
            for (int q = 0; q < j; ++q) d = fmaf(-s[tidx(j, q)], s[tidx(j, q)], d);
            const float invd = 1.0f / sqrtf(d);
            s[tidx(j, j)] = invd;
            #pragma unroll
            for (int i = j + 1; i < 16; ++i) {
                float v = s[tidx(i, j)];
                #pragma unroll
                for (int q = 0; q < j; ++q) v = fmaf(-s[tidx(i, q)], s[tidx(j, q)], v);
                s[tidx(i, j)] = v * invd;
            }
        }

        // M = L^{-1} in place (diag already inverted)
        #pragma unroll
        for (int j = 0; j < 16; ++j) {
            #pragma unroll
            for (int i = j + 1; i < 16; ++i) {
                float sum = s[tidx(i, j)] * s[tidx(j, j)];
                #pragma unroll
                for (int q = j + 1; q < i; ++q)
                    sum = fmaf(s[tidx(i, q)], s[tidx(q, j)], sum);
                s[tidx(i, j)] = -s[tidx(i, i)] * sum;
            }
        }

        // A^{-1} = M^T M in place
        #pragma unroll
        for (int j = 0; j < 16; ++j) {
            #pragma unroll
            for (int i = j; i < 16; ++i) {
                float sum = 0.0f;
                #pragma unroll
                for (int q = i; q < 16; ++q)
                    sum = fmaf(s[tidx(q, i)], s[tidx(q, j)], sum);
                s[tidx(i, j)] = sum;
            }
        }

        // writeback
        #pragma unroll
        for (int t = 0; t < 136; ++t) sm.tri[t * 67 + lane] = s[t];
    }
    __syncthreads();

    // ---- phase 4: gather-store, each thread handles elements tid and tid+128 ----
    const int e0 = tid;                 // 0..127
    const int e1 = tid + 128;           // 128..255
    const int i0 = e0 >> 4, j0 = e0 & 15;
    const int h0 = i0 > j0 ? i0 : j0, l0 = i0 + j0 - h0;
    const int trow0 = h0 * (h0 + 1) / 2 + l0;
    const int i1 = e1 >> 4, j1 = e1 & 15;
    const int h1 = i1 > j1 ? i1 : j1, l1 = i1 + j1 - h1;
    const int trow1 = h1 * (h1 + 1) / 2 + l1;

    float* gout = out + (size_t)p0 * 256;
    #pragma unroll 8
    for (int a = 0; a < 64; ++a) {
        gout[(size_t)a * 256 + e0] = sm.tri[trow0 * 67 + a];
        gout[(size_t)a * 256 + e1] = sm.tri[trow1 * 67 + a];
    }
}

extern "C" void kernel_launch(void* const* d_in, const int* in_sizes, int n_in,
                              void* d_out, int out_size, void* d_ws, size_t ws_size,
                              hipStream_t stream) {
    const float* x = (const float*)d_in[0];
    float* out = (float*)d_out;
    hipLaunchKernelGGL(fused_gram_inv, dim3(1024), dim3(128), 0, stream, x, out);
}